// Round 3
// baseline (1557.465 us; speedup 1.0000x reference)
//
#include <hip/hip_runtime.h>
#include <math.h>

// ---------------------------------------------------------------------------
// GConvNet via dst-bucketed edge partition + LDS aggregation.
// R3: 8-wide unrolled gather loop in k_agg_lds (16 independent float4 loads
// in flight per wave per iter) to convert the latency-bound random gather
// into a line-fetch-throughput-bound one. Vectorized k_deg_src loads.
//
// ws layout (dwords):
//   pd    [NBKT*CAP]            @ 0
//   cs    [NBKT]                @ PDW          (zeroed)
//   cd    [NBKT]                @ PDW+1024     (zeroed)
//   gsum  [4G]                  @ PDW+2048     (zeroed)
//   gcnt  [G]                   @ PDW+6144     (zeroed)
//   onorm [n]                   @ PDW+7168
//   ybuf  [8n]  (y1 then y2)    @ PDW+7168+n
//   hbuf  [8n]  (h1 then h2)    @ PDW+7168+9n
// ---------------------------------------------------------------------------

#define BSHIFT 10
#define BMASK  1023u
#define NBKT   1024
#define CAP    17408u
#define EPT    32            // edges per thread in partition kernels
#define PTH    1024          // threads per partition block
#define CHUNK  (PTH * EPT)   // 32768 edges per block

// ---- partition src (keys only, ushort payload) ----------------------------
__global__ __launch_bounds__(PTH) void k_part_src(const int* __restrict__ src,
                                                  unsigned short* __restrict__ ps,
                                                  unsigned int* __restrict__ cur,
                                                  int n_edges) {
    __shared__ unsigned int hist[NBKT];
    __shared__ unsigned int base[NBKT];
    const int tid = threadIdx.x;
    const int e0 = blockIdx.x * CHUNK;
    for (int i = tid; i < NBKT; i += PTH) hist[i] = 0;
    __syncthreads();
    unsigned int sv[EPT];
    unsigned int rk[EPT];
#pragma unroll
    for (int k = 0; k < EPT; ++k) {
        int e = e0 + k * PTH + tid;
        if (e < n_edges) {
            unsigned int s = (unsigned int)src[e];
            sv[k] = s;
            rk[k] = atomicAdd(&hist[s >> BSHIFT], 1u);
        } else {
            sv[k] = 0xFFFFFFFFu;
        }
    }
    __syncthreads();
    if (tid < NBKT) base[tid] = atomicAdd(&cur[tid], hist[tid]);
    __syncthreads();
#pragma unroll
    for (int k = 0; k < EPT; ++k) {
        if (sv[k] != 0xFFFFFFFFu) {
            unsigned int b = sv[k] >> BSHIFT;
            unsigned int pos = b * CAP + base[b] + rk[k];
            ps[pos] = (unsigned short)(sv[k] & BMASK);
        }
    }
}

// ---- partition dst with packed (src,dstlow) payload -----------------------
__global__ __launch_bounds__(PTH) void k_part_dst(const int* __restrict__ src,
                                                  const int* __restrict__ dst,
                                                  unsigned int* __restrict__ pd,
                                                  unsigned int* __restrict__ cur,
                                                  int n_edges) {
    __shared__ unsigned int hist[NBKT];
    __shared__ unsigned int base[NBKT];
    const int tid = threadIdx.x;
    const int e0 = blockIdx.x * CHUNK;
    for (int i = tid; i < NBKT; i += PTH) hist[i] = 0;
    __syncthreads();
    unsigned int wv[EPT];  // packed (src<<10)|(dst&1023)
    unsigned int br[EPT];  // packed (bucket<<20)|rank, 0xFFFFFFFF = invalid
#pragma unroll
    for (int k = 0; k < EPT; ++k) {
        int e = e0 + k * PTH + tid;
        if (e < n_edges) {
            unsigned int d = (unsigned int)dst[e];
            unsigned int s = (unsigned int)src[e];
            unsigned int b = d >> BSHIFT;
            wv[k] = (s << BSHIFT) | (d & BMASK);
            unsigned int r = atomicAdd(&hist[b], 1u);
            br[k] = (b << 20) | r;
        } else {
            br[k] = 0xFFFFFFFFu;
        }
    }
    __syncthreads();
    if (tid < NBKT) base[tid] = atomicAdd(&cur[tid], hist[tid]);
    __syncthreads();
#pragma unroll
    for (int k = 0; k < EPT; ++k) {
        if (br[k] != 0xFFFFFFFFu) {
            unsigned int b = br[k] >> 20;
            unsigned int r = br[k] & 0xFFFFFu;
            pd[b * CAP + base[b] + r] = wv[k];
        }
    }
}

// ---- out-degree histogram per src bucket -> onorm -------------------------
__global__ __launch_bounds__(512) void k_deg_src(const unsigned short* __restrict__ ps,
                                                 const unsigned int* __restrict__ cur,
                                                 float* __restrict__ onorm, int n_nodes) {
    __shared__ unsigned int cnt[1 << BSHIFT];
    const int b = blockIdx.x, tid = threadIdx.x;
    for (int i = tid; i < (1 << BSHIFT); i += 512) cnt[i] = 0;
    __syncthreads();
    const unsigned int n = cur[b];
    const unsigned int base = (unsigned int)b * CAP;
    const unsigned int nfull = n & ~4095u;  // 512 thr * 8 keys
    for (unsigned int i0 = 0; i0 < nfull; i0 += 4096) {
        uint4 p = *(const uint4*)(ps + base + i0 + (unsigned int)tid * 8u);
        unsigned int w[4] = {p.x, p.y, p.z, p.w};
#pragma unroll
        for (int k = 0; k < 4; ++k) {
            atomicAdd(&cnt[w[k] & 0xFFFFu], 1u);
            atomicAdd(&cnt[w[k] >> 16], 1u);
        }
    }
    for (unsigned int i = nfull + tid; i < n; i += 512) atomicAdd(&cnt[ps[base + i]], 1u);
    __syncthreads();
    for (int r = tid; r < (1 << BSHIFT); r += 512) {
        int node = (b << BSHIFT) + r;
        if (node < n_nodes) onorm[node] = rsqrtf(fmaxf((float)cnt[r], 1.0f));
    }
}

// ---- y1 = (feat @ W1) * onorm  (10 -> 8) ----------------------------------
__global__ void k_node1(const float* __restrict__ feat, const float* __restrict__ W1,
                        const float* __restrict__ onorm, float* __restrict__ y1,
                        int n_nodes) {
    int i = blockIdx.x * blockDim.x + threadIdx.x;
    if (i >= n_nodes) return;
    float on = onorm[i];
    const float* fr = feat + (size_t)i * 10;
    float f[10];
#pragma unroll
    for (int k = 0; k < 10; ++k) f[k] = fr[k];
    float acc[8];
#pragma unroll
    for (int j = 0; j < 8; ++j) acc[j] = 0.0f;
#pragma unroll
    for (int k = 0; k < 10; ++k)
#pragma unroll
        for (int j = 0; j < 8; ++j) acc[j] = fmaf(f[k], W1[k * 8 + j], acc[j]);
    float4* yo = (float4*)(y1 + (size_t)i * 8);
    yo[0] = make_float4(acc[0] * on, acc[1] * on, acc[2] * on, acc[3] * on);
    yo[1] = make_float4(acc[4] * on, acc[5] * on, acc[6] * on, acc[7] * on);
}

// ---- per-bucket aggregation: h = relu(inn * sum(y[src]) + bias) -----------
// 8 slots per thread per iteration: 16 (F=8) / 8 (F=4) independent float4
// gathers in flight before any LDS consumption -> MLP-bound, not latency.
template <int F>
__global__ __launch_bounds__(512) void k_agg_lds(const unsigned int* __restrict__ pd,
                                                 const unsigned int* __restrict__ cur,
                                                 const float* __restrict__ y,
                                                 const float* __restrict__ bias,
                                                 float* __restrict__ h, int n_nodes) {
    __shared__ float acc[(1 << BSHIFT) * F];
    __shared__ unsigned int cnt[1 << BSHIFT];
    const int b = blockIdx.x, tid = threadIdx.x;
    for (int i = tid; i < (1 << BSHIFT) * F; i += 512) acc[i] = 0.0f;
    for (int i = tid; i < (1 << BSHIFT); i += 512) cnt[i] = 0;
    __syncthreads();
    const unsigned int n = cur[b];
    const unsigned int base = (unsigned int)b * CAP;
    const unsigned int nfull = n & ~4095u;  // 512 thr * 8 slots
    for (unsigned int i0 = 0; i0 < nfull; i0 += 4096) {
        const unsigned int s0 = base + i0 + (unsigned int)tid * 8u;
        uint4 p0 = *(const uint4*)(pd + s0);
        uint4 p1 = *(const uint4*)(pd + s0 + 4);
        unsigned int w[8] = {p0.x, p0.y, p0.z, p0.w, p1.x, p1.y, p1.z, p1.w};
        float4 v0[8];
        float4 v1[8];
#pragma unroll
        for (int k = 0; k < 8; ++k) {
            const float* yr = y + (size_t)(w[k] >> BSHIFT) * F;
            v0[k] = *(const float4*)yr;
            if (F == 8) v1[k] = *(const float4*)(yr + 4);
        }
#pragma unroll
        for (int k = 0; k < 8; ++k) {
            unsigned int d = w[k] & BMASK;
            atomicAdd(&cnt[d], 1u);
            atomicAdd(&acc[d * F + 0], v0[k].x);
            atomicAdd(&acc[d * F + 1], v0[k].y);
            atomicAdd(&acc[d * F + 2], v0[k].z);
            atomicAdd(&acc[d * F + 3], v0[k].w);
            if (F == 8) {
                atomicAdd(&acc[d * F + 4], v1[k].x);
                atomicAdd(&acc[d * F + 5], v1[k].y);
                atomicAdd(&acc[d * F + 6], v1[k].z);
                atomicAdd(&acc[d * F + 7], v1[k].w);
            }
        }
    }
    for (unsigned int i = nfull + tid; i < n; i += 512) {
        unsigned int w = pd[base + i];
        unsigned int d = w & BMASK;
        unsigned int s = w >> BSHIFT;
        atomicAdd(&cnt[d], 1u);
        const float* yr = y + (size_t)s * F;
        float4 q0 = *(const float4*)yr;
        atomicAdd(&acc[d * F + 0], q0.x);
        atomicAdd(&acc[d * F + 1], q0.y);
        atomicAdd(&acc[d * F + 2], q0.z);
        atomicAdd(&acc[d * F + 3], q0.w);
        if (F == 8) {
            float4 q1 = *(const float4*)(yr + 4);
            atomicAdd(&acc[d * F + 4], q1.x);
            atomicAdd(&acc[d * F + 5], q1.y);
            atomicAdd(&acc[d * F + 6], q1.z);
            atomicAdd(&acc[d * F + 7], q1.w);
        }
    }
    __syncthreads();
    for (int r = tid; r < (1 << BSHIFT); r += 512) {
        int node = (b << BSHIFT) + r;
        if (node >= n_nodes) continue;
        float inn = rsqrtf(fmaxf((float)cnt[r], 1.0f));
        float4 o0;
        o0.x = fmaxf(fmaf(acc[r * F + 0], inn, bias[0]), 0.0f);
        o0.y = fmaxf(fmaf(acc[r * F + 1], inn, bias[1]), 0.0f);
        o0.z = fmaxf(fmaf(acc[r * F + 2], inn, bias[2]), 0.0f);
        o0.w = fmaxf(fmaf(acc[r * F + 3], inn, bias[3]), 0.0f);
        ((float4*)(h + (size_t)node * F))[0] = o0;
        if (F == 8) {
            float4 o1;
            o1.x = fmaxf(fmaf(acc[r * F + 4], inn, bias[4]), 0.0f);
            o1.y = fmaxf(fmaf(acc[r * F + 5], inn, bias[5]), 0.0f);
            o1.z = fmaxf(fmaf(acc[r * F + 6], inn, bias[6]), 0.0f);
            o1.w = fmaxf(fmaf(acc[r * F + 7], inn, bias[7]), 0.0f);
            ((float4*)(h + (size_t)node * F))[1] = o1;
        }
    }
}

// ---- y2 = (h1 @ W2) * onorm  (8 -> 4) -------------------------------------
__global__ void k_node2(const float* __restrict__ h1, const float* __restrict__ W2,
                        const float* __restrict__ onorm, float* __restrict__ y2,
                        int n_nodes) {
    int i = blockIdx.x * blockDim.x + threadIdx.x;
    if (i >= n_nodes) return;
    float on = onorm[i];
    const float4* hr = (const float4*)(h1 + (size_t)i * 8);
    float4 a0 = hr[0];
    float4 a1 = hr[1];
    float hv[8] = {a0.x, a0.y, a0.z, a0.w, a1.x, a1.y, a1.z, a1.w};
    float acc[4] = {0.0f, 0.0f, 0.0f, 0.0f};
#pragma unroll
    for (int k = 0; k < 8; ++k)
#pragma unroll
        for (int j = 0; j < 4; ++j) acc[j] = fmaf(hv[k], W2[k * 4 + j], acc[j]);
    ((float4*)(y2 + (size_t)i * 4))[0] =
        make_float4(acc[0] * on, acc[1] * on, acc[2] * on, acc[3] * on);
}

// ---- per-graph pooling (gid sorted -> wave-segmented reduce) --------------
__global__ void k_pool(const float* __restrict__ h2, const int* __restrict__ gid,
                       float* __restrict__ gsum, float* __restrict__ gcnt, int n_nodes) {
    int i = blockIdx.x * blockDim.x + threadIdx.x;
    int lane = threadIdx.x & 63;
    int g = -1;
    float v0 = 0.f, v1 = 0.f, v2 = 0.f, v3 = 0.f, c = 0.f;
    if (i < n_nodes) {
        float4 a = ((const float4*)(h2 + (size_t)i * 4))[0];
        v0 = a.x; v1 = a.y; v2 = a.z; v3 = a.w;
        c = 1.0f;
        g = gid[i];
    }
#pragma unroll
    for (int s = 1; s < 64; s <<= 1) {
        int go   = __shfl_down(g, s);
        float t0 = __shfl_down(v0, s);
        float t1 = __shfl_down(v1, s);
        float t2 = __shfl_down(v2, s);
        float t3 = __shfl_down(v3, s);
        float tc = __shfl_down(c, s);
        if (lane + s < 64 && go == g) {
            v0 += t0; v1 += t1; v2 += t2; v3 += t3; c += tc;
        }
    }
    int gp = __shfl_up(g, 1);
    bool head = (lane == 0) || (gp != g);
    if (g >= 0 && head) {
        unsafeAtomicAdd(&gsum[g * 4 + 0], v0);
        unsafeAtomicAdd(&gsum[g * 4 + 1], v1);
        unsafeAtomicAdd(&gsum[g * 4 + 2], v2);
        unsafeAtomicAdd(&gsum[g * 4 + 3], v3);
        unsafeAtomicAdd(&gcnt[g], c);
    }
}

__global__ void k_final(const float* __restrict__ gsum, const float* __restrict__ gcnt,
                        const float* __restrict__ Wo, const float* __restrict__ bo,
                        float* __restrict__ out, int n_graphs) {
    int i = blockIdx.x * blockDim.x + threadIdx.x;
    if (i >= n_graphs) return;
    float inv = 1.0f / fmaxf(gcnt[i], 1.0f);
    float z = bo[0];
#pragma unroll
    for (int j = 0; j < 4; ++j) z = fmaf(gsum[i * 4 + j] * inv, Wo[j], z);
    out[i] = 1.0f / (1.0f + expf(-z));
}

extern "C" void kernel_launch(void* const* d_in, const int* in_sizes, int n_in,
                              void* d_out, int out_size, void* d_ws, size_t ws_size,
                              hipStream_t stream) {
    const float* feat = (const float*)d_in[0];
    const int*   src  = (const int*)d_in[1];
    const int*   dst  = (const int*)d_in[2];
    const int*   gid  = (const int*)d_in[3];
    const float* W1   = (const float*)d_in[4];
    const float* b1   = (const float*)d_in[5];
    const float* W2   = (const float*)d_in[6];
    const float* b2   = (const float*)d_in[7];
    const float* Wo   = (const float*)d_in[8];
    const float* bo   = (const float*)d_in[9];
    float* out = (float*)d_out;

    const int n_nodes  = in_sizes[0] / 10;
    const int n_edges  = in_sizes[1];
    const int n_graphs = out_size;
    const int nbk_used = (n_nodes + (1 << BSHIFT) - 1) >> BSHIFT;

    unsigned int* ws32 = (unsigned int*)d_ws;
    const size_t PDW = (size_t)NBKT * CAP;
    unsigned int*   pd    = ws32;
    unsigned short* ps    = (unsigned short*)ws32;   // aliases pd (time-multiplexed)
    unsigned int*   cs    = ws32 + PDW;
    unsigned int*   cd    = cs + NBKT;
    float*          gsum  = (float*)(cd + NBKT);
    float*          gcnt  = gsum + 4 * (size_t)n_graphs;
    float*          onorm = gcnt + n_graphs;
    float*          ybuf  = onorm + n_nodes;
    float*          hbuf  = ybuf + 8 * (size_t)n_nodes;

    hipMemsetAsync(cs, 0, (2 * NBKT + 5 * (size_t)n_graphs) * sizeof(unsigned int), stream);

    const int nchunk = (n_edges + CHUNK - 1) / CHUNK;
    const int B = 256;

    k_part_src<<<nchunk, PTH, 0, stream>>>(src, ps, cs, n_edges);
    k_deg_src<<<nbk_used, 512, 0, stream>>>(ps, cs, onorm, n_nodes);
    k_part_dst<<<nchunk, PTH, 0, stream>>>(src, dst, pd, cd, n_edges);
    k_node1<<<(n_nodes + B - 1) / B, B, 0, stream>>>(feat, W1, onorm, ybuf, n_nodes);
    k_agg_lds<8><<<nbk_used, 512, 0, stream>>>(pd, cd, ybuf, b1, hbuf, n_nodes);
    k_node2<<<(n_nodes + B - 1) / B, B, 0, stream>>>(hbuf, W2, onorm, ybuf, n_nodes);
    k_agg_lds<4><<<nbk_used, 512, 0, stream>>>(pd, cd, ybuf, b2, hbuf, n_nodes);
    k_pool<<<(n_nodes + B - 1) / B, B, 0, stream>>>(hbuf, gid, gsum, gcnt, n_nodes);
    k_final<<<(n_graphs + B - 1) / B, B, 0, stream>>>(gsum, gcnt, Wo, bo, out, n_graphs);
}